// Round 11
// baseline (485.998 us; speedup 1.0000x reference)
//
#include <hip/hip_runtime.h>
#include <hip/hip_bf16.h>

typedef __hip_bfloat16 bf16;
typedef __attribute__((ext_vector_type(8))) short short8;   // 8 bf16 (4 VGPR)
typedef __attribute__((ext_vector_type(4))) float f32x4;    // MFMA acc

#define N_NODES 100000
#define N_EDGES 640000
#define N_TILES 6250      // N_NODES / 16

// ---------------------------------------------------------------------------
// Per-wave dtype detection (wave-uniform, ~1 load/lane, L2-hot after block 0).
// int64 edges: all 32 sampled high-words are 0 (values < 2^31; random int32
// would need 32 simultaneous zeros, P ~ 1e-160).
__device__ __forceinline__ int detect_is64(const int* __restrict__ idx) {
    int lane = threadIdx.x & 63;
    int v = idx[2 * (lane & 31) + 1];
    return __ballot(v == 0) == ~0ULL;
}
// f32 floats: low half-words are uniform mantissa bits -> rarely decode to a
// plausible bf16 N(0,1) exponent; bf16 data decodes in-range essentially always.
__device__ __forceinline__ int detect_f32(const unsigned* __restrict__ xw) {
    int lane = threadIdx.x & 63;
    unsigned e = (xw[lane] >> 7) & 0xFFu;
    int inr = (e >= 0x20u && e <= 0x4Fu);
    return __popcll(__ballot(inr)) < 48;   // few valid patterns => f32
}

// ---------------------------------------------------------------------------
// Edge decode: 8 edges per thread, int4 vector loads. E % 512 == 0 so the
// e0 >= E exit is wave-uniform (detect's ballot runs first, full wave).
__device__ __forceinline__ void decode8(
        const int* __restrict__ eidx, int is64, int e0, int E,
        int (&ss)[8], int (&dd)[8]) {
    if (is64) {
        int4 a0 = *(const int4*)&eidx[2 * e0];
        int4 a1 = *(const int4*)&eidx[2 * e0 + 4];
        int4 a2 = *(const int4*)&eidx[2 * e0 + 8];
        int4 a3 = *(const int4*)&eidx[2 * e0 + 12];
        int4 b0 = *(const int4*)&eidx[2 * (E + e0)];
        int4 b1 = *(const int4*)&eidx[2 * (E + e0) + 4];
        int4 b2 = *(const int4*)&eidx[2 * (E + e0) + 8];
        int4 b3 = *(const int4*)&eidx[2 * (E + e0) + 12];
        ss[0] = a0.x; ss[1] = a0.z; ss[2] = a1.x; ss[3] = a1.z;
        ss[4] = a2.x; ss[5] = a2.z; ss[6] = a3.x; ss[7] = a3.z;
        dd[0] = b0.x; dd[1] = b0.z; dd[2] = b1.x; dd[3] = b1.z;
        dd[4] = b2.x; dd[5] = b2.z; dd[6] = b3.x; dd[7] = b3.z;
    } else {
        int4 s0 = *(const int4*)&eidx[e0];
        int4 s1 = *(const int4*)&eidx[e0 + 4];
        int4 d0 = *(const int4*)&eidx[E + e0];
        int4 d1 = *(const int4*)&eidx[E + e0 + 4];
        ss[0] = s0.x; ss[1] = s0.y; ss[2] = s0.z; ss[3] = s0.w;
        ss[4] = s1.x; ss[5] = s1.y; ss[6] = s1.z; ss[7] = s1.w;
        dd[0] = d0.x; dd[1] = d0.y; dd[2] = d0.z; dd[3] = d0.w;
        dd[4] = d1.x; dd[5] = d1.y; dd[6] = d1.z; dd[7] = d1.w;
    }
}

// hist: deg[d]++ and record each edge's arrival rank (its CSR slot).
__global__ __launch_bounds__(256) void hist_kernel(
        const int* __restrict__ eidx, int* __restrict__ deg,
        int* __restrict__ rank, int E, int N) {
    const int is64 = detect_is64(eidx);
    int e0 = (blockIdx.x * 256 + threadIdx.x) * 8;
    if (e0 >= E) return;
    int ss[8], dd[8], rk[8];
    decode8(eidx, is64, e0, E, ss, dd);
#pragma unroll
    for (int c = 0; c < 8; ++c) {
        bool ok = (unsigned)ss[c] < (unsigned)N && (unsigned)dd[c] < (unsigned)N;
        rk[c] = ok ? atomicAdd(&deg[dd[c]], 1) : 0;
    }
    *(int4*)&rank[e0]     = make_int4(rk[0], rk[1], rk[2], rk[3]);
    *(int4*)&rank[e0 + 4] = make_int4(rk[4], rk[5], rk[6], rk[7]);
}

// Single-block exclusive scan: off[0..N] from deg[0..N-1]. 1024 threads,
// 98 elements each (1024*98 >= N). Two passes over deg (L2-hot).
__global__ __launch_bounds__(1024) void scan_kernel(
        const int* __restrict__ deg, int* __restrict__ off, int N) {
    __shared__ int part[1024];
    const int tid = threadIdx.x;
    const int seg0 = tid * 98;
    int sum = 0;
    for (int i = 0; i < 98; ++i) {
        int idx = seg0 + i;
        sum += (idx < N) ? deg[idx] : 0;
    }
    part[tid] = sum;
    __syncthreads();
    for (int o = 1; o < 1024; o <<= 1) {
        int t = (tid >= o) ? part[tid - o] : 0;
        __syncthreads();
        part[tid] += t;
        __syncthreads();
    }
    int run = part[tid] - sum;                  // exclusive base of segment
    if (tid == 1023) off[N] = part[1023];       // total valid edges
    for (int i = 0; i < 98; ++i) {
        int idx = seg0 + i;
        if (idx < N) { off[idx] = run; run += deg[idx]; }
    }
}

// fill: srcs[off[d] + rank[e]] = s — no atomics, independent scattered stores.
__global__ __launch_bounds__(256) void fill_kernel(
        const int* __restrict__ eidx, const int* __restrict__ off,
        const int* __restrict__ rank, int* __restrict__ srcs, int E, int N) {
    const int is64 = detect_is64(eidx);
    int e0 = (blockIdx.x * 256 + threadIdx.x) * 8;
    if (e0 >= E) return;
    int ss[8], dd[8];
    decode8(eidx, is64, e0, E, ss, dd);
    int4 r0 = *(const int4*)&rank[e0];
    int4 r1 = *(const int4*)&rank[e0 + 4];
    const int rk[8] = {r0.x, r0.y, r0.z, r0.w, r1.x, r1.y, r1.z, r1.w};
#pragma unroll
    for (int c = 0; c < 8; ++c) {
        if ((unsigned)ss[c] >= (unsigned)N || (unsigned)dd[c] >= (unsigned)N) continue;
        srcs[off[dd[c]] + rk[c]] = ss[c];
    }
}

// ---------------------------------------------------------------------------
// Gather-reduce 1 + fused combine epilogue. One wave per node, lane = dim.
// h = relu(sum(xl[src])/deg + b1 + xr)
__global__ __launch_bounds__(256) void gather1_kernel(
        const int* __restrict__ srcs, const int* __restrict__ off,
        const bf16* __restrict__ xl, const bf16* __restrict__ xr,
        const void* __restrict__ b1, bf16* __restrict__ h,
        const unsigned* __restrict__ xdet, int N) {
    const int f32 = detect_f32(xdet);
    const int node = blockIdx.x * 4 + (threadIdx.x >> 6);
    const int lane = threadIdx.x & 63;
    if (node >= N) return;
    const int a = off[node], b = off[node + 1];
    float acc = 0.f;
    for (int base = a; base < b; base += 64) {
        const int cdeg = min(b - base, 64);
        int sv = (lane < cdeg) ? srcs[base + lane] : 0;
        for (int bb = 0; bb < cdeg; bb += 8) {
            float v[8];
#pragma unroll
            for (int t = 0; t < 8; ++t) {
                int idx = bb + t;
                int s = __shfl(sv, idx < cdeg ? idx : 0);
                float val = (float)xl[(size_t)s * 64 + lane];
                v[t] = (idx < cdeg) ? val : 0.f;
            }
            acc += ((v[0] + v[1]) + (v[2] + v[3])) + ((v[4] + v[5]) + (v[6] + v[7]));
        }
    }
    const float bb = f32 ? ((const float*)b1)[lane] : (float)((const bf16*)b1)[lane];
    const float inv = 1.0f / fmaxf((float)(b - a), 1.0f);
    float v = acc * inv + bb + (float)xr[(size_t)node * 64 + lane];
    h[(size_t)node * 64 + lane] = __float2bfloat16(fmaxf(v, 0.0f));
}

// Gather-reduce 2 + fused final epilogue. Halves take even/odd edges, 32 dims.
// out = sum(hl[src])/deg + b2 + hr
__global__ __launch_bounds__(256) void gather2_kernel(
        const int* __restrict__ srcs, const int* __restrict__ off,
        const bf16* __restrict__ hl, const bf16* __restrict__ hr,
        const void* __restrict__ b2, void* __restrict__ out,
        const unsigned* __restrict__ xdet, int N) {
    const int f32 = detect_f32(xdet);
    const int node = blockIdx.x * 4 + (threadIdx.x >> 6);
    const int lane = threadIdx.x & 63;
    if (node >= N) return;
    const int j = lane & 31, half = lane >> 5;
    const int a = off[node], b = off[node + 1];
    float acc = 0.f;
    for (int base = a; base < b; base += 64) {
        const int cdeg = min(b - base, 64);
        int sv = (lane < cdeg) ? srcs[base + lane] : 0;
        for (int bb = 0; bb < cdeg; bb += 8) {
            float v[4];
#pragma unroll
            for (int t = 0; t < 4; ++t) {
                int idx = bb + half + 2 * t;
                int s = __shfl(sv, idx < cdeg ? idx : 0);
                float val = (float)hl[(size_t)s * 32 + j];
                v[t] = (idx < cdeg) ? val : 0.f;
            }
            acc += (v[0] + v[1]) + (v[2] + v[3]);
        }
    }
    acc += __shfl_down(acc, 32);
    if (half == 0) {
        const float bb = f32 ? ((const float*)b2)[j] : (float)((const bf16*)b2)[j];
        const float inv = 1.0f / fmaxf((float)(b - a), 1.0f);
        float v = acc * inv + bb + (float)hr[(size_t)node * 32 + j];
        if (f32) ((float*)out)[(size_t)node * 32 + j] = v;
        else     ((bf16*)out)[(size_t)node * 32 + j] = __float2bfloat16(v);
    }
}

// ===========================================================================
// MFMA fragment helpers (16x16x32 bf16):
//   A[m][k]: m = lane&15, k = quad*8 + j   (16B contiguous per lane)
//   B[k][n]: n = lane&15, k = quad*8 + j
//   C/D:     col = lane&15, row = quad*4 + reg
// ===========================================================================
__device__ __forceinline__ short8 load_frag(const void* base, size_t eoff, int f32) {
    if (f32) {
        const float* p = (const float*)base + eoff;
        short8 r;
#pragma unroll
        for (int j = 0; j < 8; ++j) {
            union { bf16 b; short s; } u;
            u.b = __float2bfloat16(p[j]);
            r[j] = u.s;
        }
        return r;
    }
    return *(const short8*)((const short*)base + eoff);
}

// Layer-1 GEMM: y[N,64] = x[N,128] @ W^T.  Stationary-B (16 frags = 64 VGPR),
// 1 tile/wave (6252 waves) for max TLP on the latency-bound A-loads.
__global__ __launch_bounds__(256) void lin1_kernel(
        const void* __restrict__ x, const void* __restrict__ W,
        bf16* __restrict__ y) {
    const int f32 = detect_f32((const unsigned*)x);
    const int nwaves = gridDim.x * 4;
    const int wid = blockIdx.x * 4 + (threadIdx.x >> 6);
    const int lane = threadIdx.x & 63;
    const int m = lane & 15, quad = lane >> 4;

    short8 bfr[16];
#pragma unroll
    for (int ks = 0; ks < 4; ++ks)
#pragma unroll
        for (int nt = 0; nt < 4; ++nt)
            bfr[ks * 4 + nt] =
                load_frag(W, (size_t)(nt * 16 + m) * 128 + ks * 32 + quad * 8, f32);

    for (int tile = wid; tile < N_TILES; tile += nwaves) {
        const int row0 = tile * 16;
        f32x4 acc[4];
#pragma unroll
        for (int nt = 0; nt < 4; ++nt) acc[nt] = (f32x4){0.f, 0.f, 0.f, 0.f};

        const size_t arow = (size_t)(row0 + m) * 128;
        short8 a[4];
#pragma unroll
        for (int ks = 0; ks < 4; ++ks)
            a[ks] = load_frag(x, arow + ks * 32 + quad * 8, f32);
#pragma unroll
        for (int ks = 0; ks < 4; ++ks)
#pragma unroll
            for (int nt = 0; nt < 4; ++nt)
                acc[nt] = __builtin_amdgcn_mfma_f32_16x16x32_bf16(
                    a[ks], bfr[ks * 4 + nt], acc[nt], 0, 0, 0);

#pragma unroll
        for (int reg = 0; reg < 4; ++reg) {
            const int row = row0 + quad * 4 + reg;
#pragma unroll
            for (int nt = 0; nt < 4; ++nt)
                y[(size_t)row * 64 + nt * 16 + m] = __float2bfloat16(acc[nt][reg]);
        }
    }
}

// Layer-2 dual GEMM: hl = h@W2l^T, hr = h@W2r^T.  Stationary-B (8 frags).
__global__ __launch_bounds__(256) void lin2_kernel(
        const bf16* __restrict__ h, const void* __restrict__ W2l,
        const void* __restrict__ W2r, bf16* __restrict__ hl,
        bf16* __restrict__ hr, const unsigned* __restrict__ xdet) {
    const int f32 = detect_f32(xdet);
    const int nwaves = gridDim.x * 4;
    const int wid = blockIdx.x * 4 + (threadIdx.x >> 6);
    const int lane = threadIdx.x & 63;
    const int m = lane & 15, quad = lane >> 4;

    short8 bfr[8];
#pragma unroll
    for (int ks = 0; ks < 2; ++ks)
#pragma unroll
        for (int nt = 0; nt < 4; ++nt) {
            const void* Wb = (nt < 2) ? W2l : W2r;
            bfr[ks * 4 + nt] =
                load_frag(Wb, (size_t)((nt & 1) * 16 + m) * 64 + ks * 32 + quad * 8, f32);
        }

    for (int tile = wid; tile < N_TILES; tile += nwaves) {
        const int row0 = tile * 16;
        f32x4 acc[4];
#pragma unroll
        for (int nt = 0; nt < 4; ++nt) acc[nt] = (f32x4){0.f, 0.f, 0.f, 0.f};

        const size_t arow = (size_t)(row0 + m) * 64;
        short8 a[2];
#pragma unroll
        for (int ks = 0; ks < 2; ++ks)
            a[ks] = *(const short8*)((const short*)h + arow + ks * 32 + quad * 8);
#pragma unroll
        for (int ks = 0; ks < 2; ++ks)
#pragma unroll
            for (int nt = 0; nt < 4; ++nt)
                acc[nt] = __builtin_amdgcn_mfma_f32_16x16x32_bf16(
                    a[ks], bfr[ks * 4 + nt], acc[nt], 0, 0, 0);

#pragma unroll
        for (int reg = 0; reg < 4; ++reg) {
            const int row = row0 + quad * 4 + reg;
#pragma unroll
            for (int nt = 0; nt < 4; ++nt) {
                bf16* dst = (nt < 2) ? hl : hr;
                dst[(size_t)row * 32 + (nt & 1) * 16 + m] = __float2bfloat16(acc[nt][reg]);
            }
        }
    }
}

// ---------------------------------------------------------------------------
extern "C" void kernel_launch(void* const* d_in, const int* in_sizes, int n_in,
                              void* d_out, int out_size, void* d_ws, size_t ws_size,
                              hipStream_t stream) {
    const void* x   = d_in[0];
    const int*  eix = (const int*)d_in[1];
    const void* W1l = d_in[2];
    const void* b1  = d_in[3];
    const void* W1r = d_in[4];
    const void* W2l = d_in[5];
    const void* b2  = d_in[6];
    const void* W2r = d_in[7];

    const int N = N_NODES;
    const int E = N_EDGES;

    // Workspace layout (~58 MB of 256 MiB):
    //   xl    bf16[N*64]   @ 256
    //   xr    bf16[N*64]   @ 256 + N*128
    //   h     bf16[N*64]   @ 256 + N*256
    //   hl    bf16[N*32]   @ 256 + N*384
    //   hr    bf16[N*32]   @ 256 + N*448
    //   off   int[N+4]     @ 256 + N*512
    //   deg   int[N]       @ off + (N+4)*4
    //   rank  int[E]       @ deg + N*4
    //   srcs  int[E]       @ rank + E*4
    char* ws = (char*)d_ws;
    bf16*  xl    = (bf16*)(ws + 256);
    bf16*  xr    = (bf16*)(ws + 256 + (size_t)N * 128);
    bf16*  h     = (bf16*)(ws + 256 + (size_t)N * 256);
    bf16*  hl    = (bf16*)(ws + 256 + (size_t)N * 384);
    bf16*  hr    = (bf16*)(ws + 256 + (size_t)N * 448);
    int*   off   = (int*) (ws + 256 + (size_t)N * 512);
    int*   deg   = off + (N + 4);
    int*   rank  = deg + N;
    int*   srcs  = rank + E;

    // --- CSR build: memset + hist(rank) + single-block scan + atomic-free fill
    hipMemsetAsync(deg, 0, (size_t)N * 4, stream);
    const int ge = (E / 8 + 255) / 256;   // 313
    hist_kernel<<<ge, 256, 0, stream>>>(eix, deg, rank, E, N);
    scan_kernel<<<1, 1024, 0, stream>>>(deg, off, N);
    fill_kernel<<<ge, 256, 0, stream>>>(eix, off, rank, srcs, E, N);

    const int gg = 1563;   // 6252 waves, 1 tile/wave

    // xl = x@W1l^T, xr = x@W1r^T  (stationary-B MFMA)
    lin1_kernel<<<gg, 256, 0, stream>>>(x, W1l, xl);
    lin1_kernel<<<gg, 256, 0, stream>>>(x, W1r, xr);

    // h = relu(sum(xl[src])/deg + b1 + xr)
    gather1_kernel<<<(N + 3) / 4, 256, 0, stream>>>(
        srcs, off, xl, xr, b1, h, (const unsigned*)x, N);

    // hl = h@W2l^T, hr = h@W2r^T
    lin2_kernel<<<gg, 256, 0, stream>>>(h, W2l, W2r, hl, hr, (const unsigned*)x);

    // out = sum(hl[src])/deg + b2 + hr
    gather2_kernel<<<(N + 3) / 4, 256, 0, stream>>>(
        srcs, off, hl, hr, b2, d_out, (const unsigned*)x, N);
}

// Round 12
// 304.302 us; speedup vs baseline: 1.5971x; 1.5971x over previous
//
#include <hip/hip_runtime.h>
#include <hip/hip_bf16.h>

typedef __hip_bfloat16 bf16;
typedef __attribute__((ext_vector_type(8))) short short8;   // 8 bf16 (4 VGPR)
typedef __attribute__((ext_vector_type(4))) float f32x4;    // MFMA acc

#define N_NODES 100000
#define N_EDGES 640000
#define NSB 98            // ceil(N_NODES / 1024)
#define N_TILES 6250      // N_NODES / 16

// ---------------------------------------------------------------------------
// Per-wave dtype detection (wave-uniform, ~1 load/lane, L2-hot after block 0).
__device__ __forceinline__ int detect_is64(const int* __restrict__ idx) {
    int lane = threadIdx.x & 63;
    int v = idx[2 * (lane & 31) + 1];
    return __ballot(v == 0) == ~0ULL;
}
__device__ __forceinline__ int detect_f32(const unsigned* __restrict__ xw) {
    int lane = threadIdx.x & 63;
    unsigned e = (xw[lane] >> 7) & 0xFFu;
    int inr = (e >= 0x20u && e <= 0x4Fu);
    return __popcll(__ballot(inr)) < 48;   // few valid bf16 patterns => f32
}

// ---------------------------------------------------------------------------
// Edge decode: 8 edges per thread, int4 vector loads. E % 2048 == 0.
__device__ __forceinline__ void decode8(
        const int* __restrict__ eidx, int is64, int e0, int E,
        int (&ss)[8], int (&dd)[8]) {
    if (is64) {
        int4 a0 = *(const int4*)&eidx[2 * e0];
        int4 a1 = *(const int4*)&eidx[2 * e0 + 4];
        int4 a2 = *(const int4*)&eidx[2 * e0 + 8];
        int4 a3 = *(const int4*)&eidx[2 * e0 + 12];
        int4 b0 = *(const int4*)&eidx[2 * (E + e0)];
        int4 b1 = *(const int4*)&eidx[2 * (E + e0) + 4];
        int4 b2 = *(const int4*)&eidx[2 * (E + e0) + 8];
        int4 b3 = *(const int4*)&eidx[2 * (E + e0) + 12];
        ss[0] = a0.x; ss[1] = a0.z; ss[2] = a1.x; ss[3] = a1.z;
        ss[4] = a2.x; ss[5] = a2.z; ss[6] = a3.x; ss[7] = a3.z;
        dd[0] = b0.x; dd[1] = b0.z; dd[2] = b1.x; dd[3] = b1.z;
        dd[4] = b2.x; dd[5] = b2.z; dd[6] = b3.x; dd[7] = b3.z;
    } else {
        int4 s0 = *(const int4*)&eidx[e0];
        int4 s1 = *(const int4*)&eidx[e0 + 4];
        int4 d0 = *(const int4*)&eidx[E + e0];
        int4 d1 = *(const int4*)&eidx[E + e0 + 4];
        ss[0] = s0.x; ss[1] = s0.y; ss[2] = s0.z; ss[3] = s0.w;
        ss[4] = s1.x; ss[5] = s1.y; ss[6] = s1.z; ss[7] = s1.w;
        dd[0] = d0.x; dd[1] = d0.y; dd[2] = d0.z; dd[3] = d0.w;
        dd[4] = d1.x; dd[5] = d1.y; dd[6] = d1.z; dd[7] = d1.w;
    }
}

// hist: deg[d]++ and record each edge's arrival rank (its CSR slot).
__global__ __launch_bounds__(256) void hist_kernel(
        const int* __restrict__ eidx, int* __restrict__ deg,
        int* __restrict__ rank, int E, int N) {
    const int is64 = detect_is64(eidx);
    int e0 = (blockIdx.x * 256 + threadIdx.x) * 8;
    if (e0 >= E) return;
    int ss[8], dd[8], rk[8];
    decode8(eidx, is64, e0, E, ss, dd);
#pragma unroll
    for (int c = 0; c < 8; ++c) {
        bool ok = (unsigned)ss[c] < (unsigned)N && (unsigned)dd[c] < (unsigned)N;
        rk[c] = ok ? atomicAdd(&deg[dd[c]], 1) : 0;
    }
    *(int4*)&rank[e0]     = make_int4(rk[0], rk[1], rk[2], rk[3]);
    *(int4*)&rank[e0 + 4] = make_int4(rk[4], rk[5], rk[6], rk[7]);
}

// --- Coalesced 2-level exclusive scan (Round-10 proven pattern, ~8 us) ---
__global__ __launch_bounds__(256) void scan_partial_kernel(
        const int* __restrict__ deg, int* __restrict__ off,
        int* __restrict__ bsum, int N) {
    __shared__ int ss[256];
    const int tid = threadIdx.x, blk = blockIdx.x;
    const int base = blk * 1024 + tid * 4;
    int v[4], s = 0;
    if (base + 3 < N) {
        int4 dv = *(const int4*)&deg[base];
        v[0] = dv.x; v[1] = dv.y; v[2] = dv.z; v[3] = dv.w;
    } else {
#pragma unroll
        for (int c = 0; c < 4; ++c) v[c] = (base + c < N) ? deg[base + c] : 0;
    }
#pragma unroll
    for (int c = 0; c < 4; ++c) s += v[c];
    ss[tid] = s; __syncthreads();
    for (int o = 1; o < 256; o <<= 1) {
        int t = (tid >= o) ? ss[tid - o] : 0;
        __syncthreads();
        ss[tid] += t;
        __syncthreads();
    }
    int run = ss[tid] - s;                      // exclusive
    if (tid == 255) bsum[blk] = ss[255];
#pragma unroll
    for (int c = 0; c < 4; ++c) {
        if (base + c < N) off[base + c] = run;
        run += v[c];
    }
}

__global__ void scan_bsum_kernel(int* __restrict__ bsum, int* __restrict__ off, int N) {
    __shared__ int ss[128];
    const int tid = threadIdx.x;
    int v = (tid < NSB) ? bsum[tid] : 0;
    ss[tid] = v; __syncthreads();
    for (int o = 1; o < 128; o <<= 1) {
        int t = (tid >= o) ? ss[tid - o] : 0;
        __syncthreads();
        ss[tid] += t;
        __syncthreads();
    }
    if (tid < NSB) bsum[tid] = ss[tid] - v;     // exclusive
    if (tid == 127) off[N] = ss[127];
}

__global__ __launch_bounds__(256) void scan_add_kernel(
        int* __restrict__ off, const int* __restrict__ bsum, int N) {
    const int blk = blockIdx.x, tid = threadIdx.x;
    const int add = bsum[blk];
    const int base = blk * 1024 + tid * 4;
#pragma unroll
    for (int c = 0; c < 4; ++c) {
        int i = base + c;
        if (i < N) off[i] += add;
    }
}

// fill: srcs[off[d] + rank[e]] = s — no atomics, independent scattered stores.
__global__ __launch_bounds__(256) void fill_kernel(
        const int* __restrict__ eidx, const int* __restrict__ off,
        const int* __restrict__ rank, int* __restrict__ srcs, int E, int N) {
    const int is64 = detect_is64(eidx);
    int e0 = (blockIdx.x * 256 + threadIdx.x) * 8;
    if (e0 >= E) return;
    int ss[8], dd[8];
    decode8(eidx, is64, e0, E, ss, dd);
    int4 r0 = *(const int4*)&rank[e0];
    int4 r1 = *(const int4*)&rank[e0 + 4];
    const int rk[8] = {r0.x, r0.y, r0.z, r0.w, r1.x, r1.y, r1.z, r1.w};
#pragma unroll
    for (int c = 0; c < 8; ++c) {
        if ((unsigned)ss[c] >= (unsigned)N || (unsigned)dd[c] >= (unsigned)N) continue;
        srcs[off[dd[c]] + rk[c]] = ss[c];
    }
}

// ---------------------------------------------------------------------------
// Gather-reduce 1 + fused combine epilogue. One wave per node, lane = dim.
// h = relu(sum(xl[src])/deg + b1 + xr)
__global__ __launch_bounds__(256) void gather1_kernel(
        const int* __restrict__ srcs, const int* __restrict__ off,
        const bf16* __restrict__ xl, const bf16* __restrict__ xr,
        const void* __restrict__ b1, bf16* __restrict__ h,
        const unsigned* __restrict__ xdet, int N) {
    const int f32 = detect_f32(xdet);
    const int node = blockIdx.x * 4 + (threadIdx.x >> 6);
    const int lane = threadIdx.x & 63;
    if (node >= N) return;
    const int a = off[node], b = off[node + 1];
    float acc = 0.f;
    for (int base = a; base < b; base += 64) {
        const int cdeg = min(b - base, 64);
        int sv = (lane < cdeg) ? srcs[base + lane] : 0;
        for (int bb = 0; bb < cdeg; bb += 8) {
            float v[8];
#pragma unroll
            for (int t = 0; t < 8; ++t) {
                int idx = bb + t;
                int s = __shfl(sv, idx < cdeg ? idx : 0);
                float val = (float)xl[(size_t)s * 64 + lane];
                v[t] = (idx < cdeg) ? val : 0.f;
            }
            acc += ((v[0] + v[1]) + (v[2] + v[3])) + ((v[4] + v[5]) + (v[6] + v[7]));
        }
    }
    const float bb = f32 ? ((const float*)b1)[lane] : (float)((const bf16*)b1)[lane];
    const float inv = 1.0f / fmaxf((float)(b - a), 1.0f);
    float v = acc * inv + bb + (float)xr[(size_t)node * 64 + lane];
    h[(size_t)node * 64 + lane] = __float2bfloat16(fmaxf(v, 0.0f));
}

// Gather-reduce 2 + fused final epilogue. Halves take even/odd edges, 32 dims.
// out = sum(hl[src])/deg + b2 + hr
__global__ __launch_bounds__(256) void gather2_kernel(
        const int* __restrict__ srcs, const int* __restrict__ off,
        const bf16* __restrict__ hl, const bf16* __restrict__ hr,
        const void* __restrict__ b2, void* __restrict__ out,
        const unsigned* __restrict__ xdet, int N) {
    const int f32 = detect_f32(xdet);
    const int node = blockIdx.x * 4 + (threadIdx.x >> 6);
    const int lane = threadIdx.x & 63;
    if (node >= N) return;
    const int j = lane & 31, half = lane >> 5;
    const int a = off[node], b = off[node + 1];
    float acc = 0.f;
    for (int base = a; base < b; base += 64) {
        const int cdeg = min(b - base, 64);
        int sv = (lane < cdeg) ? srcs[base + lane] : 0;
        for (int bb = 0; bb < cdeg; bb += 8) {
            float v[4];
#pragma unroll
            for (int t = 0; t < 4; ++t) {
                int idx = bb + half + 2 * t;
                int s = __shfl(sv, idx < cdeg ? idx : 0);
                float val = (float)hl[(size_t)s * 32 + j];
                v[t] = (idx < cdeg) ? val : 0.f;
            }
            acc += (v[0] + v[1]) + (v[2] + v[3]);
        }
    }
    acc += __shfl_down(acc, 32);
    if (half == 0) {
        const float bb = f32 ? ((const float*)b2)[j] : (float)((const bf16*)b2)[j];
        const float inv = 1.0f / fmaxf((float)(b - a), 1.0f);
        float v = acc * inv + bb + (float)hr[(size_t)node * 32 + j];
        if (f32) ((float*)out)[(size_t)node * 32 + j] = v;
        else     ((bf16*)out)[(size_t)node * 32 + j] = __float2bfloat16(v);
    }
}

// ===========================================================================
// MFMA fragment helpers (16x16x32 bf16):
//   A[m][k]: m = lane&15, k = quad*8 + j   (16B contiguous per lane)
//   B[k][n]: n = lane&15, k = quad*8 + j
//   C/D:     col = lane&15, row = quad*4 + reg
// ===========================================================================
__device__ __forceinline__ short8 load_frag(const void* base, size_t eoff, int f32) {
    if (f32) {
        const float* p = (const float*)base + eoff;
        short8 r;
#pragma unroll
        for (int j = 0; j < 8; ++j) {
            union { bf16 b; short s; } u;
            u.b = __float2bfloat16(p[j]);
            r[j] = u.s;
        }
        return r;
    }
    return *(const short8*)((const short*)base + eoff);
}

// Layer-1 GEMM: y[N,64] = x[N,128] @ W^T.  Stationary-B (16 frags = 64 VGPR),
// 1 tile/wave (6252 waves) for max TLP on the latency-bound A-loads.
__global__ __launch_bounds__(256) void lin1_kernel(
        const void* __restrict__ x, const void* __restrict__ W,
        bf16* __restrict__ y) {
    const int f32 = detect_f32((const unsigned*)x);
    const int nwaves = gridDim.x * 4;
    const int wid = blockIdx.x * 4 + (threadIdx.x >> 6);
    const int lane = threadIdx.x & 63;
    const int m = lane & 15, quad = lane >> 4;

    short8 bfr[16];
#pragma unroll
    for (int ks = 0; ks < 4; ++ks)
#pragma unroll
        for (int nt = 0; nt < 4; ++nt)
            bfr[ks * 4 + nt] =
                load_frag(W, (size_t)(nt * 16 + m) * 128 + ks * 32 + quad * 8, f32);

    for (int tile = wid; tile < N_TILES; tile += nwaves) {
        const int row0 = tile * 16;
        f32x4 acc[4];
#pragma unroll
        for (int nt = 0; nt < 4; ++nt) acc[nt] = (f32x4){0.f, 0.f, 0.f, 0.f};

        const size_t arow = (size_t)(row0 + m) * 128;
        short8 a[4];
#pragma unroll
        for (int ks = 0; ks < 4; ++ks)
            a[ks] = load_frag(x, arow + ks * 32 + quad * 8, f32);
#pragma unroll
        for (int ks = 0; ks < 4; ++ks)
#pragma unroll
            for (int nt = 0; nt < 4; ++nt)
                acc[nt] = __builtin_amdgcn_mfma_f32_16x16x32_bf16(
                    a[ks], bfr[ks * 4 + nt], acc[nt], 0, 0, 0);

#pragma unroll
        for (int reg = 0; reg < 4; ++reg) {
            const int row = row0 + quad * 4 + reg;
#pragma unroll
            for (int nt = 0; nt < 4; ++nt)
                y[(size_t)row * 64 + nt * 16 + m] = __float2bfloat16(acc[nt][reg]);
        }
    }
}

// Layer-2 dual GEMM: hl = h@W2l^T, hr = h@W2r^T.  Stationary-B (8 frags).
__global__ __launch_bounds__(256) void lin2_kernel(
        const bf16* __restrict__ h, const void* __restrict__ W2l,
        const void* __restrict__ W2r, bf16* __restrict__ hl,
        bf16* __restrict__ hr, const unsigned* __restrict__ xdet) {
    const int f32 = detect_f32(xdet);
    const int nwaves = gridDim.x * 4;
    const int wid = blockIdx.x * 4 + (threadIdx.x >> 6);
    const int lane = threadIdx.x & 63;
    const int m = lane & 15, quad = lane >> 4;

    short8 bfr[8];
#pragma unroll
    for (int ks = 0; ks < 2; ++ks)
#pragma unroll
        for (int nt = 0; nt < 4; ++nt) {
            const void* Wb = (nt < 2) ? W2l : W2r;
            bfr[ks * 4 + nt] =
                load_frag(Wb, (size_t)((nt & 1) * 16 + m) * 64 + ks * 32 + quad * 8, f32);
        }

    for (int tile = wid; tile < N_TILES; tile += nwaves) {
        const int row0 = tile * 16;
        f32x4 acc[4];
#pragma unroll
        for (int nt = 0; nt < 4; ++nt) acc[nt] = (f32x4){0.f, 0.f, 0.f, 0.f};

        const size_t arow = (size_t)(row0 + m) * 64;
        short8 a[2];
#pragma unroll
        for (int ks = 0; ks < 2; ++ks)
            a[ks] = *(const short8*)((const short*)h + arow + ks * 32 + quad * 8);
#pragma unroll
        for (int ks = 0; ks < 2; ++ks)
#pragma unroll
            for (int nt = 0; nt < 4; ++nt)
                acc[nt] = __builtin_amdgcn_mfma_f32_16x16x32_bf16(
                    a[ks], bfr[ks * 4 + nt], acc[nt], 0, 0, 0);

#pragma unroll
        for (int reg = 0; reg < 4; ++reg) {
            const int row = row0 + quad * 4 + reg;
#pragma unroll
            for (int nt = 0; nt < 4; ++nt) {
                bf16* dst = (nt < 2) ? hl : hr;
                dst[(size_t)row * 32 + (nt & 1) * 16 + m] = __float2bfloat16(acc[nt][reg]);
            }
        }
    }
}

// ---------------------------------------------------------------------------
extern "C" void kernel_launch(void* const* d_in, const int* in_sizes, int n_in,
                              void* d_out, int out_size, void* d_ws, size_t ws_size,
                              hipStream_t stream) {
    const void* x   = d_in[0];
    const int*  eix = (const int*)d_in[1];
    const void* W1l = d_in[2];
    const void* b1  = d_in[3];
    const void* W1r = d_in[4];
    const void* W2l = d_in[5];
    const void* b2  = d_in[6];
    const void* W2r = d_in[7];

    const int N = N_NODES;
    const int E = N_EDGES;

    // Workspace layout (~58 MB of 256 MiB):
    //   xl    bf16[N*64]   @ 256
    //   xr    bf16[N*64]   @ 256 + N*128
    //   h     bf16[N*64]   @ 256 + N*256
    //   hl    bf16[N*32]   @ 256 + N*384
    //   hr    bf16[N*32]   @ 256 + N*448
    //   off   int[N+4]     @ 256 + N*512
    //   deg   int[N]       @ off + (N+4)*4
    //   rank  int[E]       @ deg + N*4
    //   srcs  int[E]       @ rank + E*4
    //   bsum  int[NSB]     @ srcs + E*4
    char* ws = (char*)d_ws;
    bf16*  xl    = (bf16*)(ws + 256);
    bf16*  xr    = (bf16*)(ws + 256 + (size_t)N * 128);
    bf16*  h     = (bf16*)(ws + 256 + (size_t)N * 256);
    bf16*  hl    = (bf16*)(ws + 256 + (size_t)N * 384);
    bf16*  hr    = (bf16*)(ws + 256 + (size_t)N * 448);
    int*   off   = (int*) (ws + 256 + (size_t)N * 512);
    int*   deg   = off + (N + 4);
    int*   rank  = deg + N;
    int*   srcs  = rank + E;
    int*   bsum  = srcs + E;

    // --- CSR build: memset + hist(rank) + coalesced 2-level scan + fill ---
    hipMemsetAsync(deg, 0, (size_t)N * 4, stream);
    const int ge = (E / 8 + 255) / 256;   // 313
    hist_kernel<<<ge, 256, 0, stream>>>(eix, deg, rank, E, N);
    scan_partial_kernel<<<NSB, 256, 0, stream>>>(deg, off, bsum, N);
    scan_bsum_kernel<<<1, 128, 0, stream>>>(bsum, off, N);
    scan_add_kernel<<<NSB, 256, 0, stream>>>(off, bsum, N);
    fill_kernel<<<ge, 256, 0, stream>>>(eix, off, rank, srcs, E, N);

    const int gg = 1563;   // 6252 waves, 1 tile/wave

    // xl = x@W1l^T, xr = x@W1r^T  (stationary-B MFMA)
    lin1_kernel<<<gg, 256, 0, stream>>>(x, W1l, xl);
    lin1_kernel<<<gg, 256, 0, stream>>>(x, W1r, xr);

    // h = relu(sum(xl[src])/deg + b1 + xr)
    gather1_kernel<<<(N + 3) / 4, 256, 0, stream>>>(
        srcs, off, xl, xr, b1, h, (const unsigned*)x, N);

    // hl = h@W2l^T, hr = h@W2r^T
    lin2_kernel<<<gg, 256, 0, stream>>>(h, W2l, W2r, hl, hr, (const unsigned*)x);

    // out = sum(hl[src])/deg + b2 + hr
    gather2_kernel<<<(N + 3) / 4, 256, 0, stream>>>(
        srcs, off, hl, hr, b2, d_out, (const unsigned*)x, N);
}

// Round 13
// 267.619 us; speedup vs baseline: 1.8160x; 1.1371x over previous
//
#include <hip/hip_runtime.h>
#include <hip/hip_bf16.h>

typedef __hip_bfloat16 bf16;
typedef __attribute__((ext_vector_type(8))) short short8;   // 8 bf16 (4 VGPR)
typedef __attribute__((ext_vector_type(4))) float f32x4;    // MFMA acc

#define N_NODES 100000
#define N_EDGES 640000
#define NSB 98            // ceil(N_NODES / 1024)
#define N_TILES 6250      // N_NODES / 16

// ---------------------------------------------------------------------------
// Per-wave dtype detection (wave-uniform, ~1 load/lane, L2-hot after block 0).
__device__ __forceinline__ int detect_is64(const int* __restrict__ idx) {
    int lane = threadIdx.x & 63;
    int v = idx[2 * (lane & 31) + 1];
    return __ballot(v == 0) == ~0ULL;
}
__device__ __forceinline__ int detect_f32(const unsigned* __restrict__ xw) {
    int lane = threadIdx.x & 63;
    unsigned e = (xw[lane] >> 7) & 0xFFu;
    int inr = (e >= 0x20u && e <= 0x4Fu);
    return __popcll(__ballot(inr)) < 48;   // few valid bf16 patterns => f32
}

// ---------------------------------------------------------------------------
// Edge decode: 8 edges per thread, int4 vector loads. E % 2048 == 0.
__device__ __forceinline__ void decode8(
        const int* __restrict__ eidx, int is64, int e0, int E,
        int (&ss)[8], int (&dd)[8]) {
    if (is64) {
        int4 a0 = *(const int4*)&eidx[2 * e0];
        int4 a1 = *(const int4*)&eidx[2 * e0 + 4];
        int4 a2 = *(const int4*)&eidx[2 * e0 + 8];
        int4 a3 = *(const int4*)&eidx[2 * e0 + 12];
        int4 b0 = *(const int4*)&eidx[2 * (E + e0)];
        int4 b1 = *(const int4*)&eidx[2 * (E + e0) + 4];
        int4 b2 = *(const int4*)&eidx[2 * (E + e0) + 8];
        int4 b3 = *(const int4*)&eidx[2 * (E + e0) + 12];
        ss[0] = a0.x; ss[1] = a0.z; ss[2] = a1.x; ss[3] = a1.z;
        ss[4] = a2.x; ss[5] = a2.z; ss[6] = a3.x; ss[7] = a3.z;
        dd[0] = b0.x; dd[1] = b0.z; dd[2] = b1.x; dd[3] = b1.z;
        dd[4] = b2.x; dd[5] = b2.z; dd[6] = b3.x; dd[7] = b3.z;
    } else {
        int4 s0 = *(const int4*)&eidx[e0];
        int4 s1 = *(const int4*)&eidx[e0 + 4];
        int4 d0 = *(const int4*)&eidx[E + e0];
        int4 d1 = *(const int4*)&eidx[E + e0 + 4];
        ss[0] = s0.x; ss[1] = s0.y; ss[2] = s0.z; ss[3] = s0.w;
        ss[4] = s1.x; ss[5] = s1.y; ss[6] = s1.z; ss[7] = s1.w;
        dd[0] = d0.x; dd[1] = d0.y; dd[2] = d0.z; dd[3] = d0.w;
        dd[4] = d1.x; dd[5] = d1.y; dd[6] = d1.z; dd[7] = d1.w;
    }
}

// hist: deg[d]++ and record each edge's arrival rank (its CSR slot).
__global__ __launch_bounds__(256) void hist_kernel(
        const int* __restrict__ eidx, int* __restrict__ deg,
        int* __restrict__ rank, int E, int N) {
    const int is64 = detect_is64(eidx);
    int e0 = (blockIdx.x * 256 + threadIdx.x) * 8;
    if (e0 >= E) return;
    int ss[8], dd[8], rk[8];
    decode8(eidx, is64, e0, E, ss, dd);
#pragma unroll
    for (int c = 0; c < 8; ++c) {
        bool ok = (unsigned)ss[c] < (unsigned)N && (unsigned)dd[c] < (unsigned)N;
        rk[c] = ok ? atomicAdd(&deg[dd[c]], 1) : 0;
    }
    *(int4*)&rank[e0]     = make_int4(rk[0], rk[1], rk[2], rk[3]);
    *(int4*)&rank[e0 + 4] = make_int4(rk[4], rk[5], rk[6], rk[7]);
}

// --- Coalesced 2-level exclusive scan (proven ~8 us total) ---
__global__ __launch_bounds__(256) void scan_partial_kernel(
        const int* __restrict__ deg, int* __restrict__ off,
        int* __restrict__ bsum, int N) {
    __shared__ int ss[256];
    const int tid = threadIdx.x, blk = blockIdx.x;
    const int base = blk * 1024 + tid * 4;
    int v[4], s = 0;
    if (base + 3 < N) {
        int4 dv = *(const int4*)&deg[base];
        v[0] = dv.x; v[1] = dv.y; v[2] = dv.z; v[3] = dv.w;
    } else {
#pragma unroll
        for (int c = 0; c < 4; ++c) v[c] = (base + c < N) ? deg[base + c] : 0;
    }
#pragma unroll
    for (int c = 0; c < 4; ++c) s += v[c];
    ss[tid] = s; __syncthreads();
    for (int o = 1; o < 256; o <<= 1) {
        int t = (tid >= o) ? ss[tid - o] : 0;
        __syncthreads();
        ss[tid] += t;
        __syncthreads();
    }
    int run = ss[tid] - s;                      // exclusive
    if (tid == 255) bsum[blk] = ss[255];
#pragma unroll
    for (int c = 0; c < 4; ++c) {
        if (base + c < N) off[base + c] = run;
        run += v[c];
    }
}

__global__ void scan_bsum_kernel(int* __restrict__ bsum, int* __restrict__ off, int N) {
    __shared__ int ss[128];
    const int tid = threadIdx.x;
    int v = (tid < NSB) ? bsum[tid] : 0;
    ss[tid] = v; __syncthreads();
    for (int o = 1; o < 128; o <<= 1) {
        int t = (tid >= o) ? ss[tid - o] : 0;
        __syncthreads();
        ss[tid] += t;
        __syncthreads();
    }
    if (tid < NSB) bsum[tid] = ss[tid] - v;     // exclusive
    if (tid == 127) off[N] = ss[127];
}

__global__ __launch_bounds__(256) void scan_add_kernel(
        int* __restrict__ off, const int* __restrict__ bsum, int N) {
    const int blk = blockIdx.x, tid = threadIdx.x;
    const int add = bsum[blk];
    const int base = blk * 1024 + tid * 4;
#pragma unroll
    for (int c = 0; c < 4; ++c) {
        int i = base + c;
        if (i < N) off[i] += add;
    }
}

// fill: srcs[off[d] + rank[e]] = s — no atomics, independent scattered stores.
__global__ __launch_bounds__(256) void fill_kernel(
        const int* __restrict__ eidx, const int* __restrict__ off,
        const int* __restrict__ rank, int* __restrict__ srcs, int E, int N) {
    const int is64 = detect_is64(eidx);
    int e0 = (blockIdx.x * 256 + threadIdx.x) * 8;
    if (e0 >= E) return;
    int ss[8], dd[8];
    decode8(eidx, is64, e0, E, ss, dd);
    int4 r0 = *(const int4*)&rank[e0];
    int4 r1 = *(const int4*)&rank[e0 + 4];
    const int rk[8] = {r0.x, r0.y, r0.z, r0.w, r1.x, r1.y, r1.z, r1.w};
#pragma unroll
    for (int c = 0; c < 8; ++c) {
        if ((unsigned)ss[c] >= (unsigned)N || (unsigned)dd[c] >= (unsigned)N) continue;
        srcs[off[dd[c]] + rk[c]] = ss[c];
    }
}

// ---------------------------------------------------------------------------
// Gather-reduce 1 + fused combine epilogue. One wave per node, lane = dim.
// h = relu(sum(xl[src])/deg + b1 + xr)
__global__ __launch_bounds__(256) void gather1_kernel(
        const int* __restrict__ srcs, const int* __restrict__ off,
        const bf16* __restrict__ xl, const bf16* __restrict__ xr,
        const void* __restrict__ b1, bf16* __restrict__ h,
        const unsigned* __restrict__ xdet, int N) {
    const int f32 = detect_f32(xdet);
    const int node = blockIdx.x * 4 + (threadIdx.x >> 6);
    const int lane = threadIdx.x & 63;
    if (node >= N) return;
    const int a = off[node], b = off[node + 1];
    float acc = 0.f;
    for (int base = a; base < b; base += 64) {
        const int cdeg = min(b - base, 64);
        int sv = (lane < cdeg) ? srcs[base + lane] : 0;
        for (int bb = 0; bb < cdeg; bb += 8) {
            float v[8];
#pragma unroll
            for (int t = 0; t < 8; ++t) {
                int idx = bb + t;
                int s = __shfl(sv, idx < cdeg ? idx : 0);
                float val = (float)xl[(size_t)s * 64 + lane];
                v[t] = (idx < cdeg) ? val : 0.f;
            }
            acc += ((v[0] + v[1]) + (v[2] + v[3])) + ((v[4] + v[5]) + (v[6] + v[7]));
        }
    }
    const float bb = f32 ? ((const float*)b1)[lane] : (float)((const bf16*)b1)[lane];
    const float inv = 1.0f / fmaxf((float)(b - a), 1.0f);
    float v = acc * inv + bb + (float)xr[(size_t)node * 64 + lane];
    h[(size_t)node * 64 + lane] = __float2bfloat16(fmaxf(v, 0.0f));
}

// Gather-reduce 2 + fused final epilogue. Halves take even/odd edges, 32 dims.
// out = sum(hl[src])/deg + b2 + hr
__global__ __launch_bounds__(256) void gather2_kernel(
        const int* __restrict__ srcs, const int* __restrict__ off,
        const bf16* __restrict__ hl, const bf16* __restrict__ hr,
        const void* __restrict__ b2, void* __restrict__ out,
        const unsigned* __restrict__ xdet, int N) {
    const int f32 = detect_f32(xdet);
    const int node = blockIdx.x * 4 + (threadIdx.x >> 6);
    const int lane = threadIdx.x & 63;
    if (node >= N) return;
    const int j = lane & 31, half = lane >> 5;
    const int a = off[node], b = off[node + 1];
    float acc = 0.f;
    for (int base = a; base < b; base += 64) {
        const int cdeg = min(b - base, 64);
        int sv = (lane < cdeg) ? srcs[base + lane] : 0;
        for (int bb = 0; bb < cdeg; bb += 8) {
            float v[4];
#pragma unroll
            for (int t = 0; t < 4; ++t) {
                int idx = bb + half + 2 * t;
                int s = __shfl(sv, idx < cdeg ? idx : 0);
                float val = (float)hl[(size_t)s * 32 + j];
                v[t] = (idx < cdeg) ? val : 0.f;
            }
            acc += (v[0] + v[1]) + (v[2] + v[3]);
        }
    }
    acc += __shfl_down(acc, 32);
    if (half == 0) {
        const float bb = f32 ? ((const float*)b2)[j] : (float)((const bf16*)b2)[j];
        const float inv = 1.0f / fmaxf((float)(b - a), 1.0f);
        float v = acc * inv + bb + (float)hr[(size_t)node * 32 + j];
        if (f32) ((float*)out)[(size_t)node * 32 + j] = v;
        else     ((bf16*)out)[(size_t)node * 32 + j] = __float2bfloat16(v);
    }
}

// ===========================================================================
// MFMA fragment helpers (16x16x32 bf16):
//   A[m][k]: m = lane&15, k = quad*8 + j   (16B contiguous per lane)
//   B[k][n]: n = lane&15, k = quad*8 + j
//   C/D:     col = lane&15, row = quad*4 + reg
// ===========================================================================
__device__ __forceinline__ short8 load_frag(const void* base, size_t eoff, int f32) {
    if (f32) {
        const float* p = (const float*)base + eoff;
        short8 r;
#pragma unroll
        for (int j = 0; j < 8; ++j) {
            union { bf16 b; short s; } u;
            u.b = __float2bfloat16(p[j]);
            r[j] = u.s;
        }
        return r;
    }
    return *(const short8*)((const short*)base + eoff);
}

// Merged layer-1 GEMM: xl = x@W1l^T AND xr = x@W1r^T in one pass over x.
// Both weight banks stationary (32 frags = 128 VGPR); 2 tiles/wave; A loaded
// once per tile, feeds both banks (8 independent 4-MFMA chains).
__global__ __launch_bounds__(256, 2) void lin1_kernel(
        const void* __restrict__ x, const void* __restrict__ W1l,
        const void* __restrict__ W1r, bf16* __restrict__ xl,
        bf16* __restrict__ xr) {
    const int f32 = detect_f32((const unsigned*)x);
    const int nwaves = gridDim.x * 4;
    const int wid = blockIdx.x * 4 + (threadIdx.x >> 6);
    const int lane = threadIdx.x & 63;
    const int m = lane & 15, quad = lane >> 4;

    short8 bl[16], br[16];
#pragma unroll
    for (int ks = 0; ks < 4; ++ks)
#pragma unroll
        for (int nt = 0; nt < 4; ++nt) {
            const size_t wo = (size_t)(nt * 16 + m) * 128 + ks * 32 + quad * 8;
            bl[ks * 4 + nt] = load_frag(W1l, wo, f32);
            br[ks * 4 + nt] = load_frag(W1r, wo, f32);
        }

    for (int tile = wid; tile < N_TILES; tile += nwaves) {
        const int row0 = tile * 16;
        f32x4 accl[4], accr[4];
#pragma unroll
        for (int nt = 0; nt < 4; ++nt) {
            accl[nt] = (f32x4){0.f, 0.f, 0.f, 0.f};
            accr[nt] = (f32x4){0.f, 0.f, 0.f, 0.f};
        }

        const size_t arow = (size_t)(row0 + m) * 128;
        short8 a[4];
#pragma unroll
        for (int ks = 0; ks < 4; ++ks)
            a[ks] = load_frag(x, arow + ks * 32 + quad * 8, f32);
#pragma unroll
        for (int ks = 0; ks < 4; ++ks)
#pragma unroll
            for (int nt = 0; nt < 4; ++nt) {
                accl[nt] = __builtin_amdgcn_mfma_f32_16x16x32_bf16(
                    a[ks], bl[ks * 4 + nt], accl[nt], 0, 0, 0);
                accr[nt] = __builtin_amdgcn_mfma_f32_16x16x32_bf16(
                    a[ks], br[ks * 4 + nt], accr[nt], 0, 0, 0);
            }

#pragma unroll
        for (int reg = 0; reg < 4; ++reg) {
            const int row = row0 + quad * 4 + reg;
#pragma unroll
            for (int nt = 0; nt < 4; ++nt) {
                xl[(size_t)row * 64 + nt * 16 + m] = __float2bfloat16(accl[nt][reg]);
                xr[(size_t)row * 64 + nt * 16 + m] = __float2bfloat16(accr[nt][reg]);
            }
        }
    }
}

// Layer-2 dual GEMM: hl = h@W2l^T, hr = h@W2r^T.  Stationary-B (8 frags),
// 2 tiles/wave.
__global__ __launch_bounds__(256) void lin2_kernel(
        const bf16* __restrict__ h, const void* __restrict__ W2l,
        const void* __restrict__ W2r, bf16* __restrict__ hl,
        bf16* __restrict__ hr, const unsigned* __restrict__ xdet) {
    const int f32 = detect_f32(xdet);
    const int nwaves = gridDim.x * 4;
    const int wid = blockIdx.x * 4 + (threadIdx.x >> 6);
    const int lane = threadIdx.x & 63;
    const int m = lane & 15, quad = lane >> 4;

    short8 bfr[8];
#pragma unroll
    for (int ks = 0; ks < 2; ++ks)
#pragma unroll
        for (int nt = 0; nt < 4; ++nt) {
            const void* Wb = (nt < 2) ? W2l : W2r;
            bfr[ks * 4 + nt] =
                load_frag(Wb, (size_t)((nt & 1) * 16 + m) * 64 + ks * 32 + quad * 8, f32);
        }

    for (int tile = wid; tile < N_TILES; tile += nwaves) {
        const int row0 = tile * 16;
        f32x4 acc[4];
#pragma unroll
        for (int nt = 0; nt < 4; ++nt) acc[nt] = (f32x4){0.f, 0.f, 0.f, 0.f};

        const size_t arow = (size_t)(row0 + m) * 64;
        short8 a[2];
#pragma unroll
        for (int ks = 0; ks < 2; ++ks)
            a[ks] = *(const short8*)((const short*)h + arow + ks * 32 + quad * 8);
#pragma unroll
        for (int ks = 0; ks < 2; ++ks)
#pragma unroll
            for (int nt = 0; nt < 4; ++nt)
                acc[nt] = __builtin_amdgcn_mfma_f32_16x16x32_bf16(
                    a[ks], bfr[ks * 4 + nt], acc[nt], 0, 0, 0);

#pragma unroll
        for (int reg = 0; reg < 4; ++reg) {
            const int row = row0 + quad * 4 + reg;
#pragma unroll
            for (int nt = 0; nt < 4; ++nt) {
                bf16* dst = (nt < 2) ? hl : hr;
                dst[(size_t)row * 32 + (nt & 1) * 16 + m] = __float2bfloat16(acc[nt][reg]);
            }
        }
    }
}

// ---------------------------------------------------------------------------
extern "C" void kernel_launch(void* const* d_in, const int* in_sizes, int n_in,
                              void* d_out, int out_size, void* d_ws, size_t ws_size,
                              hipStream_t stream) {
    const void* x   = d_in[0];
    const int*  eix = (const int*)d_in[1];
    const void* W1l = d_in[2];
    const void* b1  = d_in[3];
    const void* W1r = d_in[4];
    const void* W2l = d_in[5];
    const void* b2  = d_in[6];
    const void* W2r = d_in[7];

    const int N = N_NODES;
    const int E = N_EDGES;

    // Workspace layout (~58 MB of 256 MiB):
    //   xl    bf16[N*64]   @ 256
    //   xr    bf16[N*64]   @ 256 + N*128
    //   h     bf16[N*64]   @ 256 + N*256
    //   hl    bf16[N*32]   @ 256 + N*384
    //   hr    bf16[N*32]   @ 256 + N*448
    //   off   int[N+4]     @ 256 + N*512
    //   deg   int[N]       @ off + (N+4)*4
    //   rank  int[E]       @ deg + N*4
    //   srcs  int[E]       @ rank + E*4
    //   bsum  int[NSB]     @ srcs + E*4
    char* ws = (char*)d_ws;
    bf16*  xl    = (bf16*)(ws + 256);
    bf16*  xr    = (bf16*)(ws + 256 + (size_t)N * 128);
    bf16*  h     = (bf16*)(ws + 256 + (size_t)N * 256);
    bf16*  hl    = (bf16*)(ws + 256 + (size_t)N * 384);
    bf16*  hr    = (bf16*)(ws + 256 + (size_t)N * 448);
    int*   off   = (int*) (ws + 256 + (size_t)N * 512);
    int*   deg   = off + (N + 4);
    int*   rank  = deg + N;
    int*   srcs  = rank + E;
    int*   bsum  = srcs + E;

    // --- CSR build: memset + hist(rank) + coalesced 2-level scan + fill ---
    hipMemsetAsync(deg, 0, (size_t)N * 4, stream);
    const int ge = (E / 8 + 255) / 256;   // 313
    hist_kernel<<<ge, 256, 0, stream>>>(eix, deg, rank, E, N);
    scan_partial_kernel<<<NSB, 256, 0, stream>>>(deg, off, bsum, N);
    scan_bsum_kernel<<<1, 128, 0, stream>>>(bsum, off, N);
    scan_add_kernel<<<NSB, 256, 0, stream>>>(off, bsum, N);
    fill_kernel<<<ge, 256, 0, stream>>>(eix, off, rank, srcs, E, N);

    const int gg = 782;   // 3128 waves, 2 tiles/wave

    // xl = x@W1l^T AND xr = x@W1r^T — one pass over x, both W banks stationary
    lin1_kernel<<<gg, 256, 0, stream>>>(x, W1l, W1r, xl, xr);

    // h = relu(sum(xl[src])/deg + b1 + xr)
    gather1_kernel<<<(N + 3) / 4, 256, 0, stream>>>(
        srcs, off, xl, xr, b1, h, (const unsigned*)x, N);

    // hl = h@W2l^T, hr = h@W2r^T
    lin2_kernel<<<gg, 256, 0, stream>>>(h, W2l, W2r, hl, hr, (const unsigned*)x);

    // out = sum(hl[src])/deg + b2 + hr
    gather2_kernel<<<(N + 3) / 4, 256, 0, stream>>>(
        srcs, off, hl, hr, b2, d_out, (const unsigned*)x, N);
}